// Round 5
// baseline (29.441 us; speedup 1.0000x reference)
//
#include <hip/hip_runtime.h>
#include <math.h>

// Time-varying windowed-sinc FIR, 33 taps. Algebra (R2 notes):
//   theta(t) = pi/4 + alpha*sin(beta*t/8000)
//   f0 = theta/pi;  f_k = w_k * sin(k*theta)/(pi*k), k=1..15 (taps +-16 vanish)
//   symmetric ->  out[b,t] = C0*x[t] + sum_k Ck*(x[t-k]+x[t+k]); rows share C.
// R5: two-kernel split. Kernel1 builds the normalized coef table ONCE per
// column (k-major [16][n] in d_ws, coalesced both ways, hw trig). Kernel2 is
// a pure streaming FIR with zero transcendentals. Discriminates
// "coef-VALU-bound" (time drops) vs "harness floor" (time flat).

constexpr int   BLOCK = 256;
constexpr int   VEC   = 4;   // output columns per thread (float4)
constexpr int   ROWS  = 2;   // batch rows per thread in FIR kernel
constexpr float PI_F  = 3.14159265358979323846f;
constexpr double PI_D = 3.14159265358979323846;

// W_TAB[k] = (0.5 + 0.5*cos(pi*k/16)) / (pi*k)
constexpr float W_TAB[16] = {
    0.0f,
    (float)((0.5 + 0.5 *  0.98078528040323044) / (PI_D *  1.0)),
    (float)((0.5 + 0.5 *  0.92387953251128674) / (PI_D *  2.0)),
    (float)((0.5 + 0.5 *  0.83146961230254524) / (PI_D *  3.0)),
    (float)((0.5 + 0.5 *  0.70710678118654752) / (PI_D *  4.0)),
    (float)((0.5 + 0.5 *  0.55557023301960222) / (PI_D *  5.0)),
    (float)((0.5 + 0.5 *  0.38268343236508977) / (PI_D *  6.0)),
    (float)((0.5 + 0.5 *  0.19509032201612827) / (PI_D *  7.0)),
    (float)((0.5 + 0.5 *  0.0                ) / (PI_D *  8.0)),
    (float)((0.5 + 0.5 * -0.19509032201612827) / (PI_D *  9.0)),
    (float)((0.5 + 0.5 * -0.38268343236508977) / (PI_D * 10.0)),
    (float)((0.5 + 0.5 * -0.55557023301960222) / (PI_D * 11.0)),
    (float)((0.5 + 0.5 * -0.70710678118654752) / (PI_D * 12.0)),
    (float)((0.5 + 0.5 * -0.83146961230254524) / (PI_D * 13.0)),
    (float)((0.5 + 0.5 * -0.92387953251128674) / (PI_D * 14.0)),
    (float)((0.5 + 0.5 * -0.98078528040323044) / (PI_D * 15.0)),
};

// ---- kernel 1: normalized coefficients, k-major table cw[k*n + t] ----
__global__ __launch_bounds__(BLOCK)
void lpf_coef_kernel(const float* __restrict__ alpha_p,
                     const float* __restrict__ beta_p,
                     float* __restrict__ cw, int n)
{
    const int t = blockIdx.x * BLOCK + threadIdx.x;
    if (t >= n) return;
    const float alpha = alpha_p[0];
    const float beta  = beta_p[0];

    const float theta = 0.25f * PI_F + alpha * __sinf(beta * (float)t * (1.0f / 8000.0f));
    const float s1 = __sinf(theta);
    const float c1 = __cosf(theta);

    float f[16];
    f[0] = theta * (float)(1.0 / PI_D);
    f[1] = s1 * W_TAB[1];
    const float two_c = 2.0f * c1;
    float skm1 = s1, skm2 = 0.0f;
    #pragma unroll
    for (int k = 2; k < 16; ++k) {
        const float sk = fmaf(two_c, skm1, -skm2);   // sin(k*theta)
        f[k] = sk * W_TAB[k];
        skm2 = skm1; skm1 = sk;
    }
    float sum = f[0];
    #pragma unroll
    for (int k = 1; k < 16; ++k) sum += 2.0f * f[k];
    const float inv = 1.0f / sum;
    #pragma unroll
    for (int k = 0; k < 16; ++k)
        cw[(size_t)k * (size_t)n + t] = f[k] * inv;   // lane-consecutive: coalesced
}

// ---- kernel 2: pure streaming FIR ----
template <bool CHECK>
__device__ __forceinline__ void fir_body(const float* __restrict__ x,
                                         const float* __restrict__ cw,
                                         float* __restrict__ out,
                                         int n, int t0, int row0)
{
    // coef load: 16 coalesced float4s; ck[k] covers columns t0..t0+3
    float4 ck[16];
    #pragma unroll
    for (int k = 0; k < 16; ++k)
        ck[k] = *(const float4*)(cw + (size_t)k * (size_t)n + t0);

    #pragma unroll
    for (int r = 0; r < ROWS; ++r) {
        const float* __restrict__ base = x + (size_t)(row0 + r) * (size_t)n;
        float w[36];                          // x[t0-16 .. t0+19]
        if (CHECK) {
            #pragma unroll
            for (int i = 0; i < 36; ++i) {
                const int idx = t0 - 16 + i;
                w[i] = (idx >= 0 && idx < n) ? base[idx] : 0.0f;
            }
        } else {
            const float4* __restrict__ p = (const float4*)(base + t0 - 16);
            #pragma unroll
            for (int q = 0; q < 9; ++q) {
                const float4 v = p[q];
                w[4*q+0] = v.x; w[4*q+1] = v.y; w[4*q+2] = v.z; w[4*q+3] = v.w;
            }
        }

        float4 res;
        float* rp = &res.x;
        const float* cp = &ck[0].x;           // cp[k*4 + o]
        #pragma unroll
        for (int o = 0; o < VEC; ++o) {
            const int ci = o + 16;
            float acc = cp[o] * w[ci];
            #pragma unroll
            for (int k = 1; k < 16; ++k)
                acc = fmaf(cp[k*4 + o], w[ci - k] + w[ci + k], acc);
            rp[o] = acc;
        }
        *(float4*)(out + (size_t)(row0 + r) * (size_t)n + t0) = res;
    }
}

__global__ __launch_bounds__(BLOCK)
void lpf_fir_kernel(const float* __restrict__ x,
                    const float* __restrict__ cw,
                    float* __restrict__ out, int n)
{
    const int t0 = (blockIdx.x * BLOCK + threadIdx.x) * VEC;
    if (t0 >= n) return;
    const int row0 = blockIdx.y * ROWS;

    if (blockIdx.x == 0 || blockIdx.x == gridDim.x - 1) {
        fir_body<true >(x, cw, out, n, t0, row0);
    } else {
        fir_body<false>(x, cw, out, n, t0, row0);
    }
}

extern "C" void kernel_launch(void* const* d_in, const int* in_sizes, int n_in,
                              void* d_out, int out_size, void* d_ws, size_t ws_size,
                              hipStream_t stream) {
    const float* x       = (const float*)d_in[0];
    const float* alpha_p = (const float*)d_in[1];
    const float* beta_p  = (const float*)d_in[2];
    float*       out     = (float*)d_out;
    float*       cw      = (float*)d_ws;     // 16 * n * 4B = 2 MB

    const int B = 64;
    const int n = in_sizes[0] / B;           // 32768

    dim3 cgrid((n + BLOCK - 1) / BLOCK);     // 128 blocks
    lpf_coef_kernel<<<cgrid, dim3(BLOCK), 0, stream>>>(alpha_p, beta_p, cw, n);

    dim3 fgrid((n + BLOCK * VEC - 1) / (BLOCK * VEC), B / ROWS);   // (32, 32)
    lpf_fir_kernel<<<fgrid, dim3(BLOCK), 0, stream>>>(x, cw, out, n);
}

// Round 7
// 22.677 us; speedup vs baseline: 1.2983x; 1.2983x over previous
//
#include <hip/hip_runtime.h>
#include <math.h>

// Time-varying windowed-sinc FIR, 33 taps. Algebra (R2 notes):
//   theta(t) = pi/4 + alpha*sin(beta*t/8000)
//   f0 = theta/pi;  f_k = w_k * sin(k*theta)/(pi*k), k=1..15 (taps +-16 vanish)
//   filter symmetric ->  out[b,t] = C0*x[t] + sum_k Ck*(x[t-k]+x[t+k])
//   sin(k*theta) via Chebyshev: s_k = 2cos(theta)*s_{k-1} - s_{k-2}
// R7 = R6 with the compile fix: nontemporal store needs a NATIVE vector type
// (clang ext_vector_type), not HIP's float4 class.
// Experiment: hw trig + NT stores on the R3 structure. Flat result => fixed
// dispatch-overhead floor confirmed (ROOFLINE next round).

constexpr int   BLOCK = 256;
constexpr int   VEC   = 4;   // output columns per thread (float4)
constexpr int   ROWS  = 4;   // batch rows per block
constexpr float PI_F  = 3.14159265358979323846f;
constexpr double PI_D = 3.14159265358979323846;

typedef float f32x4 __attribute__((ext_vector_type(4)));

// W_TAB[k] = (0.5 + 0.5*cos(pi*k/16)) / (pi*k)
constexpr float W_TAB[16] = {
    0.0f,
    (float)((0.5 + 0.5 *  0.98078528040323044) / (PI_D *  1.0)),
    (float)((0.5 + 0.5 *  0.92387953251128674) / (PI_D *  2.0)),
    (float)((0.5 + 0.5 *  0.83146961230254524) / (PI_D *  3.0)),
    (float)((0.5 + 0.5 *  0.70710678118654752) / (PI_D *  4.0)),
    (float)((0.5 + 0.5 *  0.55557023301960222) / (PI_D *  5.0)),
    (float)((0.5 + 0.5 *  0.38268343236508977) / (PI_D *  6.0)),
    (float)((0.5 + 0.5 *  0.19509032201612827) / (PI_D *  7.0)),
    (float)((0.5 + 0.5 *  0.0                ) / (PI_D *  8.0)),
    (float)((0.5 + 0.5 * -0.19509032201612827) / (PI_D *  9.0)),
    (float)((0.5 + 0.5 * -0.38268343236508977) / (PI_D * 10.0)),
    (float)((0.5 + 0.5 * -0.55557023301960222) / (PI_D * 11.0)),
    (float)((0.5 + 0.5 * -0.70710678118654752) / (PI_D * 12.0)),
    (float)((0.5 + 0.5 * -0.83146961230254524) / (PI_D * 13.0)),
    (float)((0.5 + 0.5 * -0.92387953251128674) / (PI_D * 14.0)),
    (float)((0.5 + 0.5 * -0.98078528040323044) / (PI_D * 15.0)),
};

template <bool CHECK>
__device__ __forceinline__ void lpf_body(const float* __restrict__ x,
                                         float* __restrict__ out,
                                         float alpha, float beta,
                                         int n, int t0, int row0)
{
    // ---- coefficients for the VEC output columns t0..t0+3 (hw trig) ----
    float C[VEC][16];
    #pragma unroll
    for (int o = 0; o < VEC; ++o) {
        const float tf    = (float)(t0 + o);
        const float theta = 0.25f * PI_F + alpha * __sinf(beta * tf * (1.0f / 8000.0f));
        const float s1 = __sinf(theta);
        const float c1 = __cosf(theta);

        float f[16];
        f[0] = theta * (float)(1.0 / PI_D);
        f[1] = s1 * W_TAB[1];
        const float two_c = 2.0f * c1;
        float skm1 = s1, skm2 = 0.0f;
        #pragma unroll
        for (int k = 2; k < 16; ++k) {
            const float sk = fmaf(two_c, skm1, -skm2);   // sin(k*theta)
            f[k] = sk * W_TAB[k];
            skm2 = skm1; skm1 = sk;
        }
        float sum = f[0];
        #pragma unroll
        for (int k = 1; k < 16; ++k) sum += 2.0f * f[k];
        const float inv = 1.0f / sum;
        #pragma unroll
        for (int k = 0; k < 16; ++k) C[o][k] = f[k] * inv;
    }

    // ---- FIR across ROWS batch rows ----
    #pragma unroll
    for (int r = 0; r < ROWS; ++r) {
        const float* __restrict__ base = x + (size_t)(row0 + r) * (size_t)n;
        float w[36];                         // x[t0-16 .. t0+19]
        if (CHECK) {
            #pragma unroll
            for (int i = 0; i < 36; ++i) {
                const int idx = t0 - 16 + i;
                w[i] = (idx >= 0 && idx < n) ? base[idx] : 0.0f;
            }
        } else {
            const float4* __restrict__ p = (const float4*)(base + t0 - 16);
            #pragma unroll
            for (int q = 0; q < 9; ++q) {
                const float4 v = p[q];
                w[4*q+0] = v.x; w[4*q+1] = v.y; w[4*q+2] = v.z; w[4*q+3] = v.w;
            }
        }

        f32x4 res;
        #pragma unroll
        for (int o = 0; o < VEC; ++o) {
            const int ci = o + 16;           // center index in w[]
            float acc = C[o][0] * w[ci];
            #pragma unroll
            for (int k = 1; k < 16; ++k)
                acc = fmaf(C[o][k], w[ci - k] + w[ci + k], acc);
            res[o] = acc;
        }
        __builtin_nontemporal_store(res,
            (f32x4*)(out + (size_t)(row0 + r) * (size_t)n + t0));
    }
}

__global__ __launch_bounds__(BLOCK)
void LowPassFilter_53661321396356_kernel(const float* __restrict__ x,
                                         const float* __restrict__ alpha_p,
                                         const float* __restrict__ beta_p,
                                         float* __restrict__ out,
                                         int n)
{
    const int t0 = (blockIdx.x * BLOCK + threadIdx.x) * VEC;
    if (t0 >= n) return;
    const int row0   = blockIdx.y * ROWS;
    const float alpha = alpha_p[0];
    const float beta  = beta_p[0];

    if (blockIdx.x == 0 || blockIdx.x == gridDim.x - 1) {
        lpf_body<true >(x, out, alpha, beta, n, t0, row0);
    } else {
        lpf_body<false>(x, out, alpha, beta, n, t0, row0);
    }
}

extern "C" void kernel_launch(void* const* d_in, const int* in_sizes, int n_in,
                              void* d_out, int out_size, void* d_ws, size_t ws_size,
                              hipStream_t stream) {
    const float* x       = (const float*)d_in[0];
    const float* alpha_p = (const float*)d_in[1];
    const float* beta_p  = (const float*)d_in[2];
    float*       out     = (float*)d_out;

    const int B = 64;
    const int n = in_sizes[0] / B;           // 32768

    dim3 grid((n + BLOCK * VEC - 1) / (BLOCK * VEC), B / ROWS);   // (32, 16)
    dim3 block(BLOCK);
    LowPassFilter_53661321396356_kernel<<<grid, block, 0, stream>>>(
        x, alpha_p, beta_p, out, n);
}